// Round 8
// baseline (679.540 us; speedup 1.0000x reference)
//
#include <hip/hip_runtime.h>
#include <math.h>

#define EMBED  1024
#define HIDDEN 1024
#define VOCAB  32000
#define TSTEPS 64
#define NBLK   256   // 1 block per CU, all co-resident (persistent kernel)

// ---------------------------------------------------------------------------
// ONE fused persistent kernel. R6 post-mortem: batched polls good (-48us),
// but stride-68 + j0=4*tv row mapping made the w3 ds_read_b128 8-way bank
// conflicted (SQ_LDS_BANK_CONFLICT 2.46e7 = ~40us/CU).
//
// R7 phase 3 (resubmitted R8 verbatim — R7 bench was an infra flake):
//   * row-interleaved mapping: lane tv owns w3 rows {tv + 16j}. Read quad =
//     (tv+q) mod 8 -> 16 lanes cover 8 quads x2 = conflict-free; the four
//     16-lane groups read identical addrs (broadcast). hs reads unchanged
//     (4*row quads distinct per group).
//   * fcW staging register double-buffered: chunk kc+1 global loads issued
//     right after the barrier, consumed next iteration -> HBM/L3 latency
//     hides under compute instead of serializing x16.
// Phases 1 and 2 unchanged from R6 (batched 1-RTT polls, packed-tag u64
// exchange, no memset: 0xAA never matches tags 1..64).
// ---------------------------------------------------------------------------
__global__ __launch_bounds__(256, 1) void decoder_fused(
    const int*   __restrict__ caps,
    const float* __restrict__ feat,
    const float* __restrict__ table,
    const float* __restrict__ Wih,
    const float* __restrict__ Whh,
    const float* __restrict__ bih,
    const float* __restrict__ bhh,
    const float* __restrict__ fcW,
    const float* __restrict__ fcb,
    unsigned long long* hs_pk,   // [64][1024] packed (tag,value)
    float* __restrict__ out)
{
    // arena reuse:
    //   phase 1: xs_s[64][132] (33792 B) + w16[16][132] (8448 B) = 42240 B
    //   phase 3: hs_s[64][68] (17408 B) + w3[128][68] (34816 B)  = 52224 B
    __shared__ __align__(16) char arena[52224];
    __shared__ float xg_s[TSTEPS][16];
    __shared__ float h_s[2][HIDDEN];
    __shared__ int   caps_s[TSTEPS];

    int tid = threadIdx.x;
    int b   = blockIdx.x;

    // ---- phase-2 weight prefetch issued first (hides HBM under phase 1)
    int lane = tid & 63;
    int wv   = tid >> 6;          // output sub-index 0..3 (one per wave)
    int g    = lane >> 4;         // gate index 0..3 (i,f,g,o)
    int c16  = lane & 15;
    int hj   = 4 * b + wv;
    const float4* wrow = (const float4*)(Whh + ((size_t)g * HIDDEN + hj) * HIDDEN);
    float4 wreg[16];
#pragma unroll
    for (int k = 0; k < 16; ++k) wreg[k] = wrow[c16 + 16 * k];

    if (tid < TSTEPS) caps_s[tid] = caps[tid];

    // ================= phase 1: xg_s[t][r] for this block's 16 columns ====
    {
        float (*xs_s)[132] = (float (*)[132])arena;            // 64 x 132
        float (*w16)[132]  = (float (*)[132])(arena + 33792);  // 16 x 132
        int jl = tid & 15;        // r = g*4+w
        int tg = tid >> 4;        // 16 groups x 4 timesteps
        float acc4[4] = {0.f, 0.f, 0.f, 0.f};
        __syncthreads();          // caps_s visible

        for (int c = 0; c < 8; ++c) {
            __syncthreads();
            for (int idx = tid; idx < 64 * 32; idx += 256) {
                int r = idx >> 5, f4 = idx & 31;
                const float* src = (r == 0)
                    ? (feat + c * 128)
                    : (table + (size_t)caps_s[r - 1] * EMBED + c * 128);
                *((float4*)&xs_s[r][f4 * 4]) = ((const float4*)src)[f4];
            }
            for (int idx = tid; idx < 16 * 32; idx += 256) {
                int r = idx >> 5, f4 = idx & 31;
                int jr = (r >> 2) * HIDDEN + 4 * b + (r & 3);
                *((float4*)&w16[r][f4 * 4]) =
                    ((const float4*)(Wih + (size_t)jr * EMBED + c * 128))[f4];
            }
            __syncthreads();
            for (int f4 = 0; f4 < 32; ++f4) {
                float4 w = *((const float4*)&w16[jl][f4 * 4]);
#pragma unroll
                for (int k = 0; k < 4; ++k) {
                    float4 x4 = *((const float4*)&xs_s[tg * 4 + k][f4 * 4]);
                    acc4[k] += w.x * x4.x + w.y * x4.y + w.z * x4.z + w.w * x4.w;
                }
            }
        }
        int jrow = (jl >> 2) * HIDDEN + 4 * b + (jl & 3);
        float bias = bih[jrow] + bhh[jrow];
#pragma unroll
        for (int k = 0; k < 4; ++k) xg_s[tg * 4 + k][jl] = acc4[k] + bias;
        __syncthreads();
    }

    // ================= phase 2: sequential LSTM =================
    float cstate = 0.f;           // live in lane 0 of each wave only
    for (int t = 0; t < TSTEPS; ++t) {
        float* dst = h_s[t & 1];
        if (t == 0) {
            for (int i = tid; i < HIDDEN; i += 256) dst[i] = 0.f;
        } else {
            const unsigned long long* hsrc = hs_pk + (size_t)(t - 1) * HIDDEN;
            unsigned want = (unsigned)t;   // producer stored tag (t-1)+1 = t
            unsigned long long x0, x1, x2, x3;
            // batched poll: issue ALL 4 loads, then check -> 1 RTT/iteration
            for (;;) {
                x0 = __hip_atomic_load(hsrc + tid, __ATOMIC_RELAXED,
                                       __HIP_MEMORY_SCOPE_AGENT);
                x1 = __hip_atomic_load(hsrc + tid + 256, __ATOMIC_RELAXED,
                                       __HIP_MEMORY_SCOPE_AGENT);
                x2 = __hip_atomic_load(hsrc + tid + 512, __ATOMIC_RELAXED,
                                       __HIP_MEMORY_SCOPE_AGENT);
                x3 = __hip_atomic_load(hsrc + tid + 768, __ATOMIC_RELAXED,
                                       __HIP_MEMORY_SCOPE_AGENT);
                bool ok = ((unsigned)(x0 >> 32) == want) &
                          ((unsigned)(x1 >> 32) == want) &
                          ((unsigned)(x2 >> 32) == want) &
                          ((unsigned)(x3 >> 32) == want);
                if (ok) break;
                __builtin_amdgcn_s_sleep(1);
            }
            dst[tid]       = __uint_as_float((unsigned)x0);
            dst[tid + 256] = __uint_as_float((unsigned)x1);
            dst[tid + 512] = __uint_as_float((unsigned)x2);
            dst[tid + 768] = __uint_as_float((unsigned)x3);
        }
        __syncthreads();

        float4 a = {0.f, 0.f, 0.f, 0.f};
#pragma unroll
        for (int k = 0; k < 16; ++k) {
            float4 w = wreg[k];
            const float* hv = &dst[(c16 + 16 * k) * 4];
            a.x += w.x * hv[0];
            a.y += w.y * hv[1];
            a.z += w.z * hv[2];
            a.w += w.w * hv[3];
        }
        float sum = (a.x + a.y) + (a.z + a.w);
        sum += __shfl_xor(sum, 1);
        sum += __shfl_xor(sum, 2);
        sum += __shfl_xor(sum, 4);
        sum += __shfl_xor(sum, 8);
        float s0 = __shfl(sum, 0);
        float s1 = __shfl(sum, 16);
        float s2 = __shfl(sum, 32);
        float s3 = __shfl(sum, 48);

        if (lane == 0) {
            float gi = s0 + xg_s[t][wv];
            float gf = s1 + xg_s[t][4 + wv];
            float gg = s2 + xg_s[t][8 + wv];
            float go = s3 + xg_s[t][12 + wv];
            float i_ = 1.f / (1.f + expf(-gi));
            float f_ = 1.f / (1.f + expf(-gf));
            float g_ = tanhf(gg);
            float o_ = 1.f / (1.f + expf(-go));
            cstate = f_ * cstate + i_ * g_;
            float hv = o_ * tanhf(cstate);
            unsigned long long pk =
                ((unsigned long long)(unsigned)(t + 1) << 32) |
                (unsigned long long)__float_as_uint(hv);
            __hip_atomic_store(hs_pk + (size_t)t * HIDDEN + hj, pk,
                               __ATOMIC_RELAXED, __HIP_MEMORY_SCOPE_AGENT);
        }
        // no trailing barrier: h_s double-buffered, xg_s read-only
    }
    __syncthreads();

    // ================= phase 3: logits for 128 vocab rows =================
    if (b >= 250) return;         // 250 * 128 = 32000
    float (*hs_s)[68] = (float (*)[68])arena;             // 64 x 68
    float (*w3)[68]   = (float (*)[68])(arena + 17408);   // 128 x 68
    int tv = tid & 15;            // w3 row lane: owns rows {tv + 16j}
    int tq = tid >> 4;            // hs row group: rows tq*4 .. tq*4+3
    int i0 = tq * 4;
    int v0 = b * 128;
    float acc[4][8];
#pragma unroll
    for (int i = 0; i < 4; ++i)
#pragma unroll
        for (int j = 0; j < 8; ++j) acc[i][j] = 0.f;

    int jcol  = tid & 63;         // hs column within chunk (wave-contiguous)
    int tbase = tid >> 6;         // hs rows tbase + 4*i

    // register double-buffer for fcW staging
    float4 wf[8];
#pragma unroll
    for (int i = 0; i < 8; ++i) {
        int idx = tid + i * 256;
        int r = idx >> 4, f4 = idx & 15;
        wf[i] = ((const float4*)(fcW + (size_t)(v0 + r) * HIDDEN))[f4];
    }

    for (int kc = 0; kc < 16; ++kc) {   // K in chunks of 64
        // stage hs chunk [64][64]: batched tag-poll, 16 words/thread, ~1 RTT
        unsigned long long v[16];
        {
            const unsigned long long* src = hs_pk + kc * 64 + jcol;
            for (;;) {
#pragma unroll
                for (int i = 0; i < 16; ++i)
                    v[i] = __hip_atomic_load(src + (size_t)(tbase + 4 * i) * HIDDEN,
                                             __ATOMIC_RELAXED,
                                             __HIP_MEMORY_SCOPE_AGENT);
                bool ok = true;
#pragma unroll
                for (int i = 0; i < 16; ++i)
                    ok &= ((unsigned)(v[i] >> 32) == (unsigned)(tbase + 4 * i + 1));
                if (ok) break;
                __builtin_amdgcn_s_sleep(8);
            }
        }
        __syncthreads();   // previous iteration done reading w3 / hs_s
#pragma unroll
        for (int i = 0; i < 8; ++i) {
            int idx = tid + i * 256;
            int r = idx >> 4, f4 = idx & 15;
            *((float4*)&w3[r][f4 * 4]) = wf[i];
        }
#pragma unroll
        for (int i = 0; i < 16; ++i)
            hs_s[tbase + 4 * i][jcol] = __uint_as_float((unsigned)v[i]);
        __syncthreads();
        // prefetch next fcW chunk (consumed next iteration; latency hides
        // under the compute loop below)
        if (kc < 15) {
#pragma unroll
            for (int i = 0; i < 8; ++i) {
                int idx = tid + i * 256;
                int r = idx >> 4, f4 = idx & 15;
                wf[i] = ((const float4*)(fcW + (size_t)(v0 + r) * HIDDEN +
                                         (kc + 1) * 64))[f4];
            }
        }
        for (int q = 0; q < 16; ++q) {
            float4 hv4[4];
#pragma unroll
            for (int i = 0; i < 4; ++i)
                hv4[i] = *((const float4*)&hs_s[i0 + i][q * 4]);
#pragma unroll
            for (int j = 0; j < 8; ++j) {
                // row tv+16j: quad (tv+q)&7 -> 8 quads x 2-way = conflict-free
                float4 w4 = *((const float4*)&w3[tv + 16 * j][q * 4]);
#pragma unroll
                for (int i = 0; i < 4; ++i) {
                    acc[i][j] += w4.x * hv4[i].x + w4.y * hv4[i].y +
                                 w4.z * hv4[i].z + w4.w * hv4[i].w;
                }
            }
        }
    }
#pragma unroll
    for (int j = 0; j < 8; ++j) {
        float bj = fcb[v0 + tv + 16 * j];
#pragma unroll
        for (int i = 0; i < 4; ++i)
            out[(size_t)(i0 + i) * VOCAB + v0 + tv + 16 * j] = acc[i][j] + bj;
    }
}

// ---------------------------------------------------------------------------
extern "C" void kernel_launch(void* const* d_in, const int* in_sizes, int n_in,
                              void* d_out, int out_size, void* d_ws, size_t ws_size,
                              hipStream_t stream) {
    const int*   caps  = (const int*)  d_in[0];
    const float* feat  = (const float*)d_in[1];
    const float* table = (const float*)d_in[2];
    const float* Wih   = (const float*)d_in[3];
    const float* Whh   = (const float*)d_in[4];
    const float* bih   = (const float*)d_in[5];
    const float* bhh   = (const float*)d_in[6];
    const float* fcW   = (const float*)d_in[7];
    const float* fcb   = (const float*)d_in[8];
    float* out = (float*)d_out;

    // Workspace: only hs_pk [64][1024] u64 (512 KB). No memset needed:
    // 0xAA poison never matches a valid tag (1..64).
    unsigned long long* hs_pk = (unsigned long long*)d_ws;

    decoder_fused<<<NBLK, 256, 0, stream>>>(caps, feat, table, Wih, Whh,
                                            bih, bhh, fcW, fcb, hs_pk, out);
}

// Round 10
// 673.403 us; speedup vs baseline: 1.0091x; 1.0091x over previous
//
#include <hip/hip_runtime.h>
#include <math.h>

#define EMBED  1024
#define HIDDEN 1024
#define VOCAB  32000
#define TSTEPS 64
#define NBLK   256   // 1 block per CU, all co-resident (persistent kernel)

// ---------------------------------------------------------------------------
// ONE fused persistent kernel. R8 post-mortem: tv+16j row-interleave killed
// the LDS bank conflicts (2.46e7 -> 8192) but its scalar strided epilogue
// inflated WRITE_SIZE 10MB -> 50MB (half-line segments + RMW).
//
// R9/R10 (R9 failed to compile: s_sleep needs a constant-int arg; fixed by
// branching to two constant call sites — no other change):
//   * phase-3 epilogue: acc(+bias) -> LDS ot[64][132] (bank-checked 2-way,
//     free) -> coalesced float4 stores, each 32-lane half-wave = 512B of
//     full contiguous lines. Compute mapping unchanged (conflict-free).
//   * phase-2 poll backoff: first miss sleeps short, later misses sleep
//     longer. 256 blocks polling the same 64 LLC lines every ~600cy likely
//     congests the fabric the producers' stores arbitrate into; backoff
//     costs <=0.1us/step, upside ~1us/step if congestion-limited.
// Phases 1/2 otherwise unchanged (batched 1-RTT polls, packed-tag u64
// exchange, no memset: 0xAA never matches tags 1..64).
// ---------------------------------------------------------------------------
__global__ __launch_bounds__(256, 1) void decoder_fused(
    const int*   __restrict__ caps,
    const float* __restrict__ feat,
    const float* __restrict__ table,
    const float* __restrict__ Wih,
    const float* __restrict__ Whh,
    const float* __restrict__ bih,
    const float* __restrict__ bhh,
    const float* __restrict__ fcW,
    const float* __restrict__ fcb,
    unsigned long long* hs_pk,   // [64][1024] packed (tag,value)
    float* __restrict__ out)
{
    // arena reuse:
    //   phase 1: xs_s[64][132] (33792 B) + w16[16][132] (8448 B) = 42240 B
    //   phase 3: hs_s[64][68] (17408 B) + w3[128][68] (34816 B)  = 52224 B
    //   phase 3 epilogue: ot[64][132] (33792 B) at arena+17408 (over w3)
    __shared__ __align__(16) char arena[52224];
    __shared__ float xg_s[TSTEPS][16];
    __shared__ float h_s[2][HIDDEN];
    __shared__ int   caps_s[TSTEPS];

    int tid = threadIdx.x;
    int b   = blockIdx.x;

    // ---- phase-2 weight prefetch issued first (hides HBM under phase 1)
    int lane = tid & 63;
    int wv   = tid >> 6;          // output sub-index 0..3 (one per wave)
    int g    = lane >> 4;         // gate index 0..3 (i,f,g,o)
    int c16  = lane & 15;
    int hj   = 4 * b + wv;
    const float4* wrow = (const float4*)(Whh + ((size_t)g * HIDDEN + hj) * HIDDEN);
    float4 wreg[16];
#pragma unroll
    for (int k = 0; k < 16; ++k) wreg[k] = wrow[c16 + 16 * k];

    if (tid < TSTEPS) caps_s[tid] = caps[tid];

    // ================= phase 1: xg_s[t][r] for this block's 16 columns ====
    {
        float (*xs_s)[132] = (float (*)[132])arena;            // 64 x 132
        float (*w16)[132]  = (float (*)[132])(arena + 33792);  // 16 x 132
        int jl = tid & 15;        // r = g*4+w
        int tg = tid >> 4;        // 16 groups x 4 timesteps
        float acc4[4] = {0.f, 0.f, 0.f, 0.f};
        __syncthreads();          // caps_s visible

        for (int c = 0; c < 8; ++c) {
            __syncthreads();
            for (int idx = tid; idx < 64 * 32; idx += 256) {
                int r = idx >> 5, f4 = idx & 31;
                const float* src = (r == 0)
                    ? (feat + c * 128)
                    : (table + (size_t)caps_s[r - 1] * EMBED + c * 128);
                *((float4*)&xs_s[r][f4 * 4]) = ((const float4*)src)[f4];
            }
            for (int idx = tid; idx < 16 * 32; idx += 256) {
                int r = idx >> 5, f4 = idx & 31;
                int jr = (r >> 2) * HIDDEN + 4 * b + (r & 3);
                *((float4*)&w16[r][f4 * 4]) =
                    ((const float4*)(Wih + (size_t)jr * EMBED + c * 128))[f4];
            }
            __syncthreads();
            for (int f4 = 0; f4 < 32; ++f4) {
                float4 w = *((const float4*)&w16[jl][f4 * 4]);
#pragma unroll
                for (int k = 0; k < 4; ++k) {
                    float4 x4 = *((const float4*)&xs_s[tg * 4 + k][f4 * 4]);
                    acc4[k] += w.x * x4.x + w.y * x4.y + w.z * x4.z + w.w * x4.w;
                }
            }
        }
        int jrow = (jl >> 2) * HIDDEN + 4 * b + (jl & 3);
        float bias = bih[jrow] + bhh[jrow];
#pragma unroll
        for (int k = 0; k < 4; ++k) xg_s[tg * 4 + k][jl] = acc4[k] + bias;
        __syncthreads();
    }

    // ================= phase 2: sequential LSTM =================
    float cstate = 0.f;           // live in lane 0 of each wave only
    for (int t = 0; t < TSTEPS; ++t) {
        float* dst = h_s[t & 1];
        if (t == 0) {
            for (int i = tid; i < HIDDEN; i += 256) dst[i] = 0.f;
        } else {
            const unsigned long long* hsrc = hs_pk + (size_t)(t - 1) * HIDDEN;
            unsigned want = (unsigned)t;   // producer stored tag (t-1)+1 = t
            unsigned long long x0, x1, x2, x3;
            // batched poll (1 RTT/round) + backoff after the first miss
            int spin = 0;
            for (;;) {
                x0 = __hip_atomic_load(hsrc + tid, __ATOMIC_RELAXED,
                                       __HIP_MEMORY_SCOPE_AGENT);
                x1 = __hip_atomic_load(hsrc + tid + 256, __ATOMIC_RELAXED,
                                       __HIP_MEMORY_SCOPE_AGENT);
                x2 = __hip_atomic_load(hsrc + tid + 512, __ATOMIC_RELAXED,
                                       __HIP_MEMORY_SCOPE_AGENT);
                x3 = __hip_atomic_load(hsrc + tid + 768, __ATOMIC_RELAXED,
                                       __HIP_MEMORY_SCOPE_AGENT);
                bool ok = ((unsigned)(x0 >> 32) == want) &
                          ((unsigned)(x1 >> 32) == want) &
                          ((unsigned)(x2 >> 32) == want) &
                          ((unsigned)(x3 >> 32) == want);
                if (ok) break;
                if (spin == 0) {
                    __builtin_amdgcn_s_sleep(1);
                    spin = 1;
                } else {
                    __builtin_amdgcn_s_sleep(8);
                }
            }
            dst[tid]       = __uint_as_float((unsigned)x0);
            dst[tid + 256] = __uint_as_float((unsigned)x1);
            dst[tid + 512] = __uint_as_float((unsigned)x2);
            dst[tid + 768] = __uint_as_float((unsigned)x3);
        }
        __syncthreads();

        float4 a = {0.f, 0.f, 0.f, 0.f};
#pragma unroll
        for (int k = 0; k < 16; ++k) {
            float4 w = wreg[k];
            const float* hv = &dst[(c16 + 16 * k) * 4];
            a.x += w.x * hv[0];
            a.y += w.y * hv[1];
            a.z += w.z * hv[2];
            a.w += w.w * hv[3];
        }
        float sum = (a.x + a.y) + (a.z + a.w);
        sum += __shfl_xor(sum, 1);
        sum += __shfl_xor(sum, 2);
        sum += __shfl_xor(sum, 4);
        sum += __shfl_xor(sum, 8);
        float s0 = __shfl(sum, 0);
        float s1 = __shfl(sum, 16);
        float s2 = __shfl(sum, 32);
        float s3 = __shfl(sum, 48);

        if (lane == 0) {
            float gi = s0 + xg_s[t][wv];
            float gf = s1 + xg_s[t][4 + wv];
            float gg = s2 + xg_s[t][8 + wv];
            float go = s3 + xg_s[t][12 + wv];
            float i_ = 1.f / (1.f + expf(-gi));
            float f_ = 1.f / (1.f + expf(-gf));
            float g_ = tanhf(gg);
            float o_ = 1.f / (1.f + expf(-go));
            cstate = f_ * cstate + i_ * g_;
            float hv = o_ * tanhf(cstate);
            unsigned long long pk =
                ((unsigned long long)(unsigned)(t + 1) << 32) |
                (unsigned long long)__float_as_uint(hv);
            __hip_atomic_store(hs_pk + (size_t)t * HIDDEN + hj, pk,
                               __ATOMIC_RELAXED, __HIP_MEMORY_SCOPE_AGENT);
        }
        // no trailing barrier: h_s double-buffered, xg_s read-only
    }
    __syncthreads();

    // ================= phase 3: logits for 128 vocab rows =================
    if (b >= 250) return;         // 250 * 128 = 32000
    float (*hs_s)[68] = (float (*)[68])arena;             // 64 x 68
    float (*w3)[68]   = (float (*)[68])(arena + 17408);   // 128 x 68
    int tv = tid & 15;            // w3 row lane: owns rows {tv + 16j}
    int tq = tid >> 4;            // hs row group: rows tq*4 .. tq*4+3
    int i0 = tq * 4;
    int v0 = b * 128;
    float acc[4][8];
#pragma unroll
    for (int i = 0; i < 4; ++i)
#pragma unroll
        for (int j = 0; j < 8; ++j) acc[i][j] = 0.f;

    int jcol  = tid & 63;         // hs column within chunk (wave-contiguous)
    int tbase = tid >> 6;         // hs rows tbase + 4*i

    // register double-buffer for fcW staging
    float4 wf[8];
#pragma unroll
    for (int i = 0; i < 8; ++i) {
        int idx = tid + i * 256;
        int r = idx >> 4, f4 = idx & 15;
        wf[i] = ((const float4*)(fcW + (size_t)(v0 + r) * HIDDEN))[f4];
    }

    for (int kc = 0; kc < 16; ++kc) {   // K in chunks of 64
        // stage hs chunk [64][64]: batched tag-poll, 16 words/thread, ~1 RTT
        unsigned long long v[16];
        {
            const unsigned long long* src = hs_pk + kc * 64 + jcol;
            for (;;) {
#pragma unroll
                for (int i = 0; i < 16; ++i)
                    v[i] = __hip_atomic_load(src + (size_t)(tbase + 4 * i) * HIDDEN,
                                             __ATOMIC_RELAXED,
                                             __HIP_MEMORY_SCOPE_AGENT);
                bool ok = true;
#pragma unroll
                for (int i = 0; i < 16; ++i)
                    ok &= ((unsigned)(v[i] >> 32) == (unsigned)(tbase + 4 * i + 1));
                if (ok) break;
                __builtin_amdgcn_s_sleep(8);
            }
        }
        __syncthreads();   // previous iteration done reading w3 / hs_s
#pragma unroll
        for (int i = 0; i < 8; ++i) {
            int idx = tid + i * 256;
            int r = idx >> 4, f4 = idx & 15;
            *((float4*)&w3[r][f4 * 4]) = wf[i];
        }
#pragma unroll
        for (int i = 0; i < 16; ++i)
            hs_s[tbase + 4 * i][jcol] = __uint_as_float((unsigned)v[i]);
        __syncthreads();
        // prefetch next fcW chunk (consumed next iteration; latency hides
        // under the compute loop below)
        if (kc < 15) {
#pragma unroll
            for (int i = 0; i < 8; ++i) {
                int idx = tid + i * 256;
                int r = idx >> 4, f4 = idx & 15;
                wf[i] = ((const float4*)(fcW + (size_t)(v0 + r) * HIDDEN +
                                         (kc + 1) * 64))[f4];
            }
        }
        for (int q = 0; q < 16; ++q) {
            float4 hv4[4];
#pragma unroll
            for (int i = 0; i < 4; ++i)
                hv4[i] = *((const float4*)&hs_s[i0 + i][q * 4]);
#pragma unroll
            for (int j = 0; j < 8; ++j) {
                // row tv+16j: quad (tv+q)&7 -> 8 quads x 2-way = conflict-free
                float4 w4 = *((const float4*)&w3[tv + 16 * j][q * 4]);
#pragma unroll
                for (int i = 0; i < 4; ++i) {
                    acc[i][j] += w4.x * hv4[i].x + w4.y * hv4[i].y +
                                 w4.z * hv4[i].z + w4.w * hv4[i].w;
                }
            }
        }
    }

    // ---- epilogue: stage acc(+bias) in LDS, then coalesced float4 stores
    float (*ot)[132] = (float (*)[132])(arena + 17408);   // 64 x 132, over w3
    __syncthreads();   // all compute reads of w3/hs_s complete
#pragma unroll
    for (int j = 0; j < 8; ++j) {
        float bj = fcb[v0 + tv + 16 * j];
#pragma unroll
        for (int i = 0; i < 4; ++i)
            ot[i0 + i][tv + 16 * j] = acc[i][j] + bj;   // 2-way banks, free
    }
    __syncthreads();
    {
        int col4 = tid & 31;      // 32 float4 = 128 cols
        int row8 = tid >> 5;      // 8 rows per pass
#pragma unroll
        for (int rep = 0; rep < 8; ++rep) {
            int r = row8 + 8 * rep;
            float4 o = *((const float4*)&ot[r][col4 * 4]);
            *((float4*)&out[(size_t)r * VOCAB + v0 + col4 * 4]) = o;
        }
    }
}

// ---------------------------------------------------------------------------
extern "C" void kernel_launch(void* const* d_in, const int* in_sizes, int n_in,
                              void* d_out, int out_size, void* d_ws, size_t ws_size,
                              hipStream_t stream) {
    const int*   caps  = (const int*)  d_in[0];
    const float* feat  = (const float*)d_in[1];
    const float* table = (const float*)d_in[2];
    const float* Wih   = (const float*)d_in[3];
    const float* Whh   = (const float*)d_in[4];
    const float* bih   = (const float*)d_in[5];
    const float* bhh   = (const float*)d_in[6];
    const float* fcW   = (const float*)d_in[7];
    const float* fcb   = (const float*)d_in[8];
    float* out = (float*)d_out;

    // Workspace: only hs_pk [64][1024] u64 (512 KB). No memset needed:
    // 0xAA poison never matches a valid tag (1..64).
    unsigned long long* hs_pk = (unsigned long long*)d_ws;

    decoder_fused<<<NBLK, 256, 0, stream>>>(caps, feat, table, Wih, Whh,
                                            bih, bhh, fcW, fcb, hs_pk, out);
}

// Round 11
// 653.205 us; speedup vs baseline: 1.0403x; 1.0309x over previous
//
#include <hip/hip_runtime.h>
#include <math.h>

#define EMBED  1024
#define HIDDEN 1024
#define VOCAB  32000
#define TSTEPS 64
#define NBLK   256   // 1 block per CU, all co-resident (persistent kernel)

// ---------------------------------------------------------------------------
// ONE fused persistent kernel, now 1024 threads/block (R11).
//
// R10 post-mortem: WRITE_SIZE stayed ~50MB with a coalesced epilogue -> the
// R8 regression was the wf[8] register prefetch SPILLING to scratch (VGPR
// pinned at 104), not the store pattern. Prefetch dropped.
// Occupancy was 11.9% = 1 wave/SIMD: phase 3 (~200us) sat at ~7x its
// LDS/VALU floor on pure latency stalls. 1024 thr/block = 4 waves/SIMD.
//
// Phase 1: 1 output/thread (tg=tid>>4 timestep, jl=tid&15 col); same
//          per-output FMA order as before -> bit-identical.
// Phase 2: gemv/activation byte-identical in threads 0..255; waves 4..15
//          barrier-only (wave-uniform branch). All 1024 threads poll one
//          packed (tag,h) word each. Exchange unchanged: agent-scope u64
//          atomics in hs_pk[64][1024]; 0xAA poison never matches tags 1..64.
// Phase 3: blocks 0..249 own 128 vocab rows; 1t x 8v register tile
//          (tv=tid&15 owns cols {tv+16j}, tq=tid>>4 owns row tq).
//          Bank audit: w3 read = 16 distinct rows x 4-way broadcast (free),
//          hs read = 4 distinct rows x 16-way broadcast (free), staging
//          writes 2-way (free). Direct global->LDS staging, no reg prefetch.
//          Epilogue: acc -> ot[64][132] LDS bounce -> coalesced float4
//          stores (full 128B lines).
// ---------------------------------------------------------------------------
__global__ __launch_bounds__(1024, 1) void decoder_fused(
    const int*   __restrict__ caps,
    const float* __restrict__ feat,
    const float* __restrict__ table,
    const float* __restrict__ Wih,
    const float* __restrict__ Whh,
    const float* __restrict__ bih,
    const float* __restrict__ bhh,
    const float* __restrict__ fcW,
    const float* __restrict__ fcb,
    unsigned long long* hs_pk,   // [64][1024] packed (tag,value)
    float* __restrict__ out)
{
    // arena reuse:
    //   phase 1: xs_s[64][132] (33792 B) + w16[16][132] (8448 B) = 42240 B
    //   phase 3: hs_s[64][68] (17408 B) + w3[128][68] (34816 B)  = 52224 B
    //   phase 3 epilogue: ot[64][132] (33792 B) at arena+17408 (over w3)
    __shared__ __align__(16) char arena[52224];
    __shared__ float xg_s[TSTEPS][16];
    __shared__ float h_s[2][HIDDEN];
    __shared__ int   caps_s[TSTEPS];

    int tid  = threadIdx.x;
    int b    = blockIdx.x;
    int lane = tid & 63;

    // ---- phase-2 roles (threads 0..255) + weight prefetch issued first
    int wv  = tid >> 6;           // for tid<256: output sub-index 0..3
    int g   = lane >> 4;          // gate index 0..3 (i,f,g,o)
    int c16 = lane & 15;
    int hj  = 4 * b + wv;         // meaningful for tid<256
    float4 wreg[16];
    if (tid < 256) {
        const float4* wrow =
            (const float4*)(Whh + ((size_t)g * HIDDEN + hj) * HIDDEN);
#pragma unroll
        for (int k = 0; k < 16; ++k) wreg[k] = wrow[c16 + 16 * k];
    }
    if (tid < TSTEPS) caps_s[tid] = caps[tid];

    // ================= phase 1: xg_s[t][r] for this block's 16 columns ====
    {
        float (*xs_s)[132] = (float (*)[132])arena;            // 64 x 132
        float (*w16)[132]  = (float (*)[132])(arena + 33792);  // 16 x 132
        int jl = tid & 15;        // r = g*4+w
        int tg = tid >> 4;        // timestep 0..63
        float acc1 = 0.f;
        __syncthreads();          // caps_s visible

        for (int c = 0; c < 8; ++c) {
            __syncthreads();
            // stage xs chunk [64][128]: 2048 float4, 2 per thread
#pragma unroll
            for (int s = 0; s < 2; ++s) {
                int idx = tid + s * 1024;
                int r = idx >> 5, f4 = idx & 31;
                const float* src = (r == 0)
                    ? (feat + c * 128)
                    : (table + (size_t)caps_s[r - 1] * EMBED + c * 128);
                *((float4*)&xs_s[r][f4 * 4]) = ((const float4*)src)[f4];
            }
            // stage the block's 16 W_ih row-chunks: 512 float4
            if (tid < 512) {
                int r = tid >> 5, f4 = tid & 31;
                int jr = (r >> 2) * HIDDEN + 4 * b + (r & 3);
                *((float4*)&w16[r][f4 * 4]) =
                    ((const float4*)(Wih + (size_t)jr * EMBED + c * 128))[f4];
            }
            __syncthreads();
            for (int f4 = 0; f4 < 32; ++f4) {
                float4 w = *((const float4*)&w16[jl][f4 * 4]);
                float4 x = *((const float4*)&xs_s[tg][f4 * 4]);
                acc1 += w.x * x.x + w.y * x.y + w.z * x.z + w.w * x.w;
            }
        }
        int jrow = (jl >> 2) * HIDDEN + 4 * b + (jl & 3);
        xg_s[tg][jl] = acc1 + bih[jrow] + bhh[jrow];
        __syncthreads();
    }

    // ================= phase 2: sequential LSTM =================
    float cstate = 0.f;           // live in lane 0 of waves 0..3 only
    for (int t = 0; t < TSTEPS; ++t) {
        float* dst = h_s[t & 1];
        if (t == 0) {
            dst[tid] = 0.f;       // 1024 threads cover HIDDEN exactly
        } else {
            const unsigned long long* src =
                hs_pk + (size_t)(t - 1) * HIDDEN + tid;
            unsigned want = (unsigned)t;   // producer stored tag (t-1)+1 = t
            unsigned long long x;
            for (;;) {
                x = __hip_atomic_load(src, __ATOMIC_RELAXED,
                                      __HIP_MEMORY_SCOPE_AGENT);
                if ((unsigned)(x >> 32) == want) break;
                __builtin_amdgcn_s_sleep(1);
            }
            dst[tid] = __uint_as_float((unsigned)x);
        }
        __syncthreads();

        if (tid < 256) {          // wave-uniform: waves 4..15 skip to barrier
            float4 a = {0.f, 0.f, 0.f, 0.f};
#pragma unroll
            for (int k = 0; k < 16; ++k) {
                float4 w = wreg[k];
                const float* hv = &dst[(c16 + 16 * k) * 4];
                a.x += w.x * hv[0];
                a.y += w.y * hv[1];
                a.z += w.z * hv[2];
                a.w += w.w * hv[3];
            }
            float sum = (a.x + a.y) + (a.z + a.w);
            sum += __shfl_xor(sum, 1);
            sum += __shfl_xor(sum, 2);
            sum += __shfl_xor(sum, 4);
            sum += __shfl_xor(sum, 8);
            float s0 = __shfl(sum, 0);
            float s1 = __shfl(sum, 16);
            float s2 = __shfl(sum, 32);
            float s3 = __shfl(sum, 48);

            if (lane == 0) {
                float gi = s0 + xg_s[t][wv];
                float gf = s1 + xg_s[t][4 + wv];
                float gg = s2 + xg_s[t][8 + wv];
                float go = s3 + xg_s[t][12 + wv];
                float i_ = 1.f / (1.f + expf(-gi));
                float f_ = 1.f / (1.f + expf(-gf));
                float g_ = tanhf(gg);
                float o_ = 1.f / (1.f + expf(-go));
                cstate = f_ * cstate + i_ * g_;
                float hv = o_ * tanhf(cstate);
                unsigned long long pk =
                    ((unsigned long long)(unsigned)(t + 1) << 32) |
                    (unsigned long long)__float_as_uint(hv);
                __hip_atomic_store(hs_pk + (size_t)t * HIDDEN + hj, pk,
                                   __ATOMIC_RELAXED, __HIP_MEMORY_SCOPE_AGENT);
            }
        }
        // no trailing barrier: h_s double-buffered, xg_s read-only
    }
    __syncthreads();

    // ================= phase 3: logits for 128 vocab rows =================
    if (b >= 250) return;         // 250 * 128 = 32000
    float (*hs_s)[68] = (float (*)[68])arena;             // 64 x 68
    float (*w3)[68]   = (float (*)[68])(arena + 17408);   // 128 x 68
    int tv = tid & 15;            // owns cols {tv + 16j}
    int tq = tid >> 4;            // owns row tq (0..63)
    int v0 = b * 128;
    float acc[8];
#pragma unroll
    for (int j = 0; j < 8; ++j) acc[j] = 0.f;

    int jcol  = tid & 63;         // hs staging column (wave-contiguous)
    int trow0 = tid >> 6;         // hs staging rows trow0 + 16*i (0..15)

    for (int kc = 0; kc < 16; ++kc) {   // K in chunks of 64
        // stage hs chunk [64][64]: batched tag-poll, 4 words/thread
        unsigned long long v4[4];
        {
            const unsigned long long* src = hs_pk + kc * 64 + jcol;
            for (;;) {
#pragma unroll
                for (int i = 0; i < 4; ++i)
                    v4[i] = __hip_atomic_load(
                        src + (size_t)(trow0 + 16 * i) * HIDDEN,
                        __ATOMIC_RELAXED, __HIP_MEMORY_SCOPE_AGENT);
                bool ok = true;
#pragma unroll
                for (int i = 0; i < 4; ++i)
                    ok &= ((unsigned)(v4[i] >> 32) ==
                           (unsigned)(trow0 + 16 * i + 1));
                if (ok) break;
                __builtin_amdgcn_s_sleep(8);
            }
        }
        __syncthreads();   // previous iteration done reading w3 / hs_s
#pragma unroll
        for (int i = 0; i < 4; ++i)
            hs_s[trow0 + 16 * i][jcol] = __uint_as_float((unsigned)v4[i]);
        // stage fcW chunk [128][64]: 2048 float4, 2 per thread, coalesced
#pragma unroll
        for (int s = 0; s < 2; ++s) {
            int idx = tid + s * 1024;
            int r = idx >> 4, f4 = idx & 15;
            *((float4*)&w3[r][f4 * 4]) =
                ((const float4*)(fcW + (size_t)(v0 + r) * HIDDEN + kc * 64))[f4];
        }
        __syncthreads();
        for (int q = 0; q < 16; ++q) {
            float4 hv = *((const float4*)&hs_s[tq][q * 4]);   // 4 rows x bcast
#pragma unroll
            for (int j = 0; j < 8; ++j) {
                float4 w4 = *((const float4*)&w3[tv + 16 * j][q * 4]); // free
                acc[j] += w4.x * hv.x + w4.y * hv.y +
                          w4.z * hv.z + w4.w * hv.w;
            }
        }
    }

    // ---- epilogue: stage acc(+bias) in LDS, then coalesced float4 stores
    float (*ot)[132] = (float (*)[132])(arena + 17408);   // 64 x 132, over w3
    __syncthreads();   // all compute reads of w3/hs_s complete
#pragma unroll
    for (int j = 0; j < 8; ++j)
        ot[tq][tv + 16 * j] = acc[j] + fcb[v0 + tv + 16 * j];  // 2-way, free
    __syncthreads();
    {
        int col4 = tid & 31;      // 32 float4 = 128 cols
        int row  = tid >> 5;      // 0..31
#pragma unroll
        for (int rep = 0; rep < 2; ++rep) {
            int r = row + 32 * rep;
            float4 o = *((const float4*)&ot[r][col4 * 4]);
            *((float4*)&out[(size_t)r * VOCAB + v0 + col4 * 4]) = o;
        }
    }
}

// ---------------------------------------------------------------------------
extern "C" void kernel_launch(void* const* d_in, const int* in_sizes, int n_in,
                              void* d_out, int out_size, void* d_ws, size_t ws_size,
                              hipStream_t stream) {
    const int*   caps  = (const int*)  d_in[0];
    const float* feat  = (const float*)d_in[1];
    const float* table = (const float*)d_in[2];
    const float* Wih   = (const float*)d_in[3];
    const float* Whh   = (const float*)d_in[4];
    const float* bih   = (const float*)d_in[5];
    const float* bhh   = (const float*)d_in[6];
    const float* fcW   = (const float*)d_in[7];
    const float* fcb   = (const float*)d_in[8];
    float* out = (float*)d_out;

    // Workspace: only hs_pk [64][1024] u64 (512 KB). No memset needed:
    // 0xAA poison never matches a valid tag (1..64).
    unsigned long long* hs_pk = (unsigned long long*)d_ws;

    decoder_fused<<<NBLK, 1024, 0, stream>>>(caps, feat, table, Wih, Whh,
                                             bih, bhh, fcW, fcb, hs_pk, out);
}